// Round 1
// baseline (110.802 us; speedup 1.0000x reference)
//
#include <hip/hip_runtime.h>
#include <hip/hip_bf16.h>

#define H_DIM   64
#define T_STEPS 128
#define B_TOT   4096
#define BB      16
#define AK      200   // padded A-row stride in ushorts (192 + 8): 400B, 16B-aligned, bank-conflict-light
#define NTHREADS 256

typedef __attribute__((ext_vector_type(8))) short short8;
typedef __attribute__((ext_vector_type(4))) float f32x4;

__device__ __forceinline__ ushort f2bf(float f) {
    unsigned u = __float_as_uint(f);
    u = (u + 0x7fffu + ((u >> 16) & 1u)) >> 16;   // RNE, finite inputs only
    return (ushort)u;
}
__device__ __forceinline__ float bf2f(ushort s) {
    return __uint_as_float(((unsigned)s) << 16);
}
__device__ __forceinline__ float fast_sigmoid(float x) {
    float e = __expf(-x);
    return __builtin_amdgcn_rcpf(1.0f + e);
}
__device__ __forceinline__ float fast_tanh(float x) {
    float ax = fminf(fabsf(x), 15.0f);            // clamp: c can be O(100), exp(2c) would overflow
    float e2 = __expf(2.0f * ax);
    float t = 1.0f - 2.0f * __builtin_amdgcn_rcpf(e2 + 1.0f);
    return copysignf(t, x);
}

// A = [x (64) | h_hi (64) | h_lo (64)] bf16, K=192. Weights live in registers as
// B-fragments; W_hh fragments are reused for the h_lo correction term.
__global__ __launch_bounds__(NTHREADS) void lstm_fused(
    const int* __restrict__ inst, const float* __restrict__ embed,
    const float* __restrict__ Wih, const float* __restrict__ Whh,
    const float* __restrict__ bih, const float* __restrict__ bhh,
    float* __restrict__ out)
{
    __shared__ __align__(16) ushort sA[2][BB][AK];
    __shared__ int sInst[BB * T_STEPS];

    const int tid  = (int)threadIdx.x;
    const int w    = tid >> 6;     // wave 0..3 -> owns h-cols w*16..w*16+15
    const int l    = tid & 63;
    const int lrow = l & 15;       // A-row (m) for reads / n-col for B-frags & C/D
    const int lk   = l >> 4;       // k-block
    const int b0   = (int)blockIdx.x * BB;

    // stage this block's instruction indices (16 rows x 128 steps, contiguous)
    for (int i = tid; i < BB * T_STEPS; i += NTHREADS)
        sInst[i] = inst[b0 * T_STEPS + i];
    __syncthreads();

    // weight B-fragments: wf[gate][kf]; kf 0,1 -> W_ih k:0..63 ; kf 2,3 -> W_hh k:0..63
    // B[k][n] = W[n][k]; lane holds n = lrow (out col), k = kf*32 + lk*8 + j (contiguous)
    short8 wf[4][4];
    float bias[4];
#pragma unroll
    for (int gi = 0; gi < 4; ++gi) {
        const int col = gi * 64 + w * 16 + lrow;       // gate output column 0..255
        bias[gi] = bih[col] + bhh[col];
#pragma unroll
        for (int kf = 0; kf < 4; ++kf) {
            const float* src = (kf < 2 ? Wih : Whh) + (long)col * H_DIM + (kf & 1) * 32 + lk * 8;
            short8 v;
#pragma unroll
            for (int j = 0; j < 8; ++j) v[j] = (short)f2bf(src[j]);
            wf[gi][kf] = v;
        }
    }

    // zero h_hi + h_lo region of buffer 0 (h0 = 0)
    for (int i = tid; i < BB * 128; i += NTHREADS) {
        const int r = i >> 7, c = i & 127;
        sA[0][r][64 + c] = 0;
    }

    // embedding gather mapping: thread -> (row, 4-float column chunk)
    const int gr = tid >> 4;
    const int gc = tid & 15;
    {
        const int idx = sInst[gr * T_STEPS + 0];
        const float4 xv = *reinterpret_cast<const float4*>(embed + (long)idx * H_DIM + gc * 4);
        ushort4 xb = make_ushort4(f2bf(xv.x), f2bf(xv.y), f2bf(xv.z), f2bf(xv.w));
        *reinterpret_cast<ushort4*>(&sA[0][gr][gc * 4]) = xb;
    }
    __syncthreads();

    f32x4 creg = {0.f, 0.f, 0.f, 0.f};   // c in D-layout: row = lk*4+r, col = w*16+lrow
    f32x4 hreg = {0.f, 0.f, 0.f, 0.f};

    for (int t = 0; t < T_STEPS; ++t) {
        const int buf = t & 1;

        // prefetch next step's embedding row chunk (global -> reg), hidden under MFMA
        float4 xv = {0.f, 0.f, 0.f, 0.f};
        const bool pf = (t + 1 < T_STEPS);
        if (pf) {
            const int idx = sInst[gr * T_STEPS + t + 1];
            xv = *reinterpret_cast<const float4*>(embed + (long)idx * H_DIM + gc * 4);
        }

        // A-fragments: lane reads A[m=lrow][k = kf*32 + lk*8 + 0..7] (16B contiguous)
        short8 a[6];
#pragma unroll
        for (int kf = 0; kf < 6; ++kf)
            a[kf] = *reinterpret_cast<const short8*>(&sA[buf][lrow][kf * 32 + lk * 8]);

        // gates = A @ W^T + (b_ih + b_hh); acc seeded with bias (same for all rows)
        f32x4 acc[4];
#pragma unroll
        for (int gi = 0; gi < 4; ++gi) {
            f32x4 accv = {bias[gi], bias[gi], bias[gi], bias[gi]};
            accv = __builtin_amdgcn_mfma_f32_16x16x32_bf16(a[0], wf[gi][0], accv, 0, 0, 0);
            accv = __builtin_amdgcn_mfma_f32_16x16x32_bf16(a[1], wf[gi][1], accv, 0, 0, 0);
            accv = __builtin_amdgcn_mfma_f32_16x16x32_bf16(a[2], wf[gi][2], accv, 0, 0, 0);
            accv = __builtin_amdgcn_mfma_f32_16x16x32_bf16(a[3], wf[gi][3], accv, 0, 0, 0);
            accv = __builtin_amdgcn_mfma_f32_16x16x32_bf16(a[4], wf[gi][2], accv, 0, 0, 0);  // h_lo
            accv = __builtin_amdgcn_mfma_f32_16x16x32_bf16(a[5], wf[gi][3], accv, 0, 0, 0);  // h_lo
            acc[gi] = accv;
        }

        // cell update, f32, in-register (gate order i,f,g,o)
#pragma unroll
        for (int r = 0; r < 4; ++r) {
            const float iv = fast_sigmoid(acc[0][r]);
            const float fv = fast_sigmoid(acc[1][r]);
            const float gv = fast_tanh(acc[2][r]);
            const float ov = fast_sigmoid(acc[3][r]);
            const float cn = fv * creg[r] + iv * gv;
            creg[r] = cn;
            hreg[r] = ov * fast_tanh(cn);
        }

        // publish h (hi+lo bf16) and prefetched x into the other buffer
        if (pf) {
            const int ob = buf ^ 1;
            const int hcol = 64 + w * 16 + lrow;
#pragma unroll
            for (int r = 0; r < 4; ++r) {
                const int row = lk * 4 + r;
                const ushort hh = f2bf(hreg[r]);
                const ushort hl = f2bf(hreg[r] - bf2f(hh));
                sA[ob][row][hcol]      = hh;
                sA[ob][row][hcol + 64] = hl;
            }
            ushort4 xb = make_ushort4(f2bf(xv.x), f2bf(xv.y), f2bf(xv.z), f2bf(xv.w));
            *reinterpret_cast<ushort4*>(&sA[ob][gr][gc * 4]) = xb;
        }
        __syncthreads();
    }

    // final h (f32) -> out[B][H]
    const int ocol = w * 16 + lrow;
#pragma unroll
    for (int r = 0; r < 4; ++r) {
        const int row = lk * 4 + r;
        out[(long)(b0 + row) * H_DIM + ocol] = hreg[r];
    }
}

extern "C" void kernel_launch(void* const* d_in, const int* in_sizes, int n_in,
                              void* d_out, int out_size, void* d_ws, size_t ws_size,
                              hipStream_t stream) {
    const int*   inst  = (const int*)  d_in[0];
    const float* embed = (const float*)d_in[1];
    const float* Wih   = (const float*)d_in[2];
    const float* Whh   = (const float*)d_in[3];
    const float* bih   = (const float*)d_in[4];
    const float* bhh   = (const float*)d_in[5];
    float* out = (float*)d_out;

    lstm_fused<<<B_TOT / BB, NTHREADS, 0, stream>>>(inst, embed, Wih, Whh, bih, bhh, out);
}